// Round 9
// baseline (271.227 us; speedup 1.0000x reference)
//
#include <hip/hip_runtime.h>
#include <hip/hip_bf16.h>

typedef __attribute__((ext_vector_type(8))) short short8;
typedef __attribute__((ext_vector_type(4))) short short4v;
typedef __attribute__((ext_vector_type(4))) float f32x4;

namespace {
constexpr int D    = 128;
constexpr int SEQ  = 512;
constexpr int NV   = 100000;
constexpr int NN   = 2048;
constexpr int KC   = 32;                     // keys per LDS chunk (NV%KC==0!)
constexpr int CHUNK_B = KC * D * 2;          // 8192 B
constexpr int NCHUNK  = NV / KC;             // 3125 exact, no partial chunks
constexpr int CPS     = 25;                  // chunks per slice (strided map)
constexpr int NSLICE  = 128;                 // 128*25 = 3200 >= 3125
constexpr int MBLKS   = 8;                   // M blocks of 256 rows
constexpr int GRID    = MBLKS * NSLICE;      // 1024 = exactly 4/CU * 256 CU
constexpr float LOG2E = 1.4426950408889634f;
constexpr float EPSN  = 1e-12f;
}

// ---------------------------------------------------------------------------
// Prep (fused): normalize keys -> bf16 Kn; gather+normalize queries scaled by
// log2(e) -> bf16 Qn; query rows also emit tgt[n] = cos(q,k_label) in fp32.
// Zeroes sums[] + ticket counter. Grid-strided, 2 rows/wave, float4 loads.
// ---------------------------------------------------------------------------
__global__ __launch_bounds__(256)
void prep_kernel(const float* __restrict__ qemb,
                 const float* __restrict__ kemb,
                 const int*   __restrict__ loc,
                 const int*   __restrict__ labels,
                 __hip_bfloat16* __restrict__ Kn,
                 __hip_bfloat16* __restrict__ Qn,
                 float* __restrict__ tgt,
                 float* __restrict__ sums,
                 unsigned int* __restrict__ counter)
{
    const int tid  = threadIdx.x;
    const int gid0 = blockIdx.x * 256 + tid;
    if (gid0 < NN) sums[gid0] = 0.f;
    if (gid0 == NN) *counter = 0u;

    const int lane = tid & 63;
    const int half = lane >> 5;          // which of the wave's 2 rows
    const int l32  = lane & 31;
    const int wv0  = gid0 >> 6;
    const int nwv  = (gridDim.x * 256) >> 6;

    for (int wv = wv0; wv * 2 < NV + NN; wv += nwv) {
        const int row = wv * 2 + half;   // NV+NN even -> always valid

        if (row < NV) {                  // ---- key row ----
            const float* src = kemb + (size_t)row * D;
            float4 v = *(const float4*)(src + l32 * 4);
            float ss = v.x * v.x + v.y * v.y + v.z * v.z + v.w * v.w;
            #pragma unroll
            for (int m = 1; m < 32; m <<= 1) ss += __shfl_xor(ss, m);
            float inv = 1.0f / fmaxf(sqrtf(ss), EPSN);
            union { __hip_bfloat162 h2[2]; short4v s4; } u;
            u.h2[0].x = __float2bfloat16(v.x * inv);
            u.h2[0].y = __float2bfloat16(v.y * inv);
            u.h2[1].x = __float2bfloat16(v.z * inv);
            u.h2[1].y = __float2bfloat16(v.w * inv);
            *(short4v*)((char*)(Kn + (size_t)row * D) + l32 * 8) = u.s4;
        } else {                         // ---- query row (+ tgt) ----
            const int n = row - NV;
            const int b = loc[2 * n], s = loc[2 * n + 1];
            const float* q = qemb + ((size_t)b * SEQ + s) * D;
            const float* k = kemb + (size_t)labels[n] * D;
            float4 qv = *(const float4*)(q + l32 * 4);
            float4 kv = *(const float4*)(k + l32 * 4);
            float qq = qv.x * qv.x + qv.y * qv.y + qv.z * qv.z + qv.w * qv.w;
            float kk = kv.x * kv.x + kv.y * kv.y + kv.z * kv.z + kv.w * kv.w;
            float qk = qv.x * kv.x + qv.y * kv.y + qv.z * kv.z + qv.w * kv.w;
            #pragma unroll
            for (int m = 1; m < 32; m <<= 1) {
                qq += __shfl_xor(qq, m);
                kk += __shfl_xor(kk, m);
                qk += __shfl_xor(qk, m);
            }
            float invq = 1.0f / fmaxf(sqrtf(qq), EPSN);
            float scl  = LOG2E * invq;
            union { __hip_bfloat162 h2[2]; short4v s4; } u;
            u.h2[0].x = __float2bfloat16(qv.x * scl);
            u.h2[0].y = __float2bfloat16(qv.y * scl);
            u.h2[1].x = __float2bfloat16(qv.z * scl);
            u.h2[1].y = __float2bfloat16(qv.w * scl);
            *(short4v*)((char*)(Qn + (size_t)n * D) + l32 * 8) = u.s4;
            if (l32 == 0)
                tgt[n] = qk * invq / fmaxf(sqrtf(kk), EPSN);
        }
    }
}

// ---------------------------------------------------------------------------
// Main. OCCUPANCY-FIRST (r6/r8 lesson: 64-rows/wave halved LDS traffic but
// lost 2x to latency at 5-8 waves/CU; r5's 32-rows/wave at more waves/CU is
// strictly faster -> LDS BW is NOT binding, latency hiding is).
// 512 threads = 8 waves x 32 rows (qf[2][4] = 32 VGPR; r5 measured VGPR=60,
// no spill, under this exact __launch_bounds__(512,4) -- load-bearing).
// KC=32 chunks, ring-4 LDS = 32 KB -> 4 blocks/CU x 8 waves = 32 waves/CU
// (100% of cap; r5's 48 KB ring allowed only 3 blocks).
// NV = 3125*32 exactly -> no partial chunks; pad chunks (>=3125) are
// all-invalid: loads clamp, accumulate skipped, MFMA harmless.
// Strided chunk map (chunk = slice + c*NSLICE) spreads the 75 pad chunks.
// Depth-3 prefetch via global_load_lds (linear LDS dest, inverse-swizzled
// source; read phys = logical ^ ((keyrow&7)<<4)); 1 load/wave/stage ->
// counted vmcnt(2/1/0). Grid 1024 = one residency generation; bijective
// XCD decode: XCD x owns slices [16x,16x+16) with all 8 M-blocks (K
// L2-resident per XCD; r4: FETCH 208->15 MB).
// rowsum += exp2(logit): |logit|<=log2e -> fixed-shift LSE, no running max.
// Last-finished block (ticket) computes the final mean inline.
// ---------------------------------------------------------------------------
__global__ __launch_bounds__(512, 4)
void lse_main(const __hip_bfloat16* __restrict__ Kn,
              const __hip_bfloat16* __restrict__ Qn,
              const float* __restrict__ tgt,
              float* __restrict__ sums,
              unsigned int* __restrict__ counter,
              float* __restrict__ out)
{
    __shared__ char lds[4 * CHUNK_B];   // 32 KB -> 4 blocks/CU
    const int tid  = threadIdx.x;
    const int lane = tid & 63;
    const int lr   = lane & 15;
    const int lh   = lane >> 4;
    const int w    = tid >> 6;          // wave 0..7

    // Bijective XCD decode: xcd = bid&7 owns lins [128*xcd, 128*xcd+128)
    // -> slices [16*xcd, 16*xcd+16), each with all 8 mblk-blocks.
    const int bid = blockIdx.x;
    const int lin = (bid & 7) * NSLICE + (bid >> 3);
    const int slice = lin >> 3;          // 0..127
    const int mblk  = lin & 7;           // 0..7

    const int m0 = mblk * 256 + w * 32;
    const char* kbase = (const char*)Kn;

    // async stage of chunk c into ring buffer bi: LDS linear dest,
    // source pre-swizzled (rule #21: both-sides-or-neither).
    auto stage = [&](int c, int bi) {
        const int chunk = slice + c * NSLICE;    // strided chunk map
        const int keybase = chunk * KC;
        const int kic = w * 4 + lh;              // key row 0..31 (per-lane)
        const int key = min(keybase + kic, NV - 1);
        const int sb  = (lr ^ (kic & 7)) << 4;   // inverse-swizzled byte-in-row
        const char* g = kbase + (size_t)key * 256 + sb;
        const char* l = lds + bi * CHUNK_B + w * 1024;  // wave-uniform base
        __builtin_amdgcn_global_load_lds(
            (const __attribute__((address_space(1))) void*)g,
            (__attribute__((address_space(3))) void*)l, 16, 0, 0);
    };

    stage(0, 0); stage(1, 1); stage(2, 2);   // prologue depth-3

    // A-operand (Q) fragments: rows m0+rg*16+lr, k = ds*32 + lh*8 .. +8
    short8 qf[2][4];
    #pragma unroll
    for (int rg = 0; rg < 2; ++rg)
        #pragma unroll
        for (int ds = 0; ds < 4; ++ds)
            qf[rg][ds] = *(const short8*)((const short*)Qn +
                          (size_t)(m0 + rg * 16 + lr) * D + ds * 32 + lh * 8);

    float rowsum[2][4] = {};
    __syncthreads();   // one-time full drain (prologue stages + qf loads)

    for (int c = 0; c < CPS; ++c) {
        if (c + 3 < CPS) stage(c + 3, (c + 3) & 3);   // depth-3 prefetch

        const char* buf = lds + (c & 3) * CHUNK_B;
        const int chunk = slice + c * NSLICE;
        const bool valid = (chunk < NCHUNK);     // pad chunks: skip accumulate
        #pragma unroll
        for (int kg = 0; kg < 2; ++kg) {
            const int kic = kg * 16 + lr;        // key row within chunk
            const int rx  = (kic & 7) << 4;
            f32x4 acc[2] = {{0,0,0,0},{0,0,0,0}};
            #pragma unroll
            for (int ds2 = 0; ds2 < 4; ++ds2) {
                short8 bf = *(const short8*)(buf +
                              ((kic * 256 + ds2 * 64 + lh * 16) ^ rx));
                #pragma unroll
                for (int rg = 0; rg < 2; ++rg)
                    acc[rg] = __builtin_amdgcn_mfma_f32_16x16x32_bf16(
                                  qf[rg][ds2], bf, acc[rg], 0, 0, 0);
            }
            if (valid) {
                #pragma unroll
                for (int rg = 0; rg < 2; ++rg)
                    #pragma unroll
                    for (int j = 0; j < 4; ++j)
                        rowsum[rg][j] += __builtin_amdgcn_exp2f(acc[rg][j]);
            }
        }
        // counted wait (T4): stage(c+1) must have landed; up to 2 newer
        // stages (1 load each) stay in flight across the barrier.
        if (c + 3 < CPS) {
            asm volatile("s_waitcnt vmcnt(2)" ::: "memory");
            __builtin_amdgcn_s_barrier();
            asm volatile("" ::: "memory");
        } else if (c + 3 == CPS) {
            asm volatile("s_waitcnt vmcnt(1)" ::: "memory");
            __builtin_amdgcn_s_barrier();
            asm volatile("" ::: "memory");
        } else if (c + 2 == CPS) {
            asm volatile("s_waitcnt vmcnt(0)" ::: "memory");
            __builtin_amdgcn_s_barrier();
            asm volatile("" ::: "memory");
        }   // c == CPS-1: no further LDS reuse, no wait needed
    }

    // reduce partial sums across the 16 column-lanes, one atomic per row
    #pragma unroll
    for (int rg = 0; rg < 2; ++rg)
        #pragma unroll
        for (int j = 0; j < 4; ++j) {
            float v = rowsum[rg][j];
            v += __shfl_xor(v, 1);
            v += __shfl_xor(v, 2);
            v += __shfl_xor(v, 4);
            v += __shfl_xor(v, 8);
            if (lr == 0)
                atomicAdd(&sums[m0 + rg * 16 + lh * 4 + j], v);
        }

    // ---- last-block final reduction (fused final_kernel) ----
    __threadfence();                       // my atomics visible before ticket
    __syncthreads();
    __shared__ int ticket_s;
    if (tid == 0) ticket_s = (int)atomicAdd(counter, 1u);
    __syncthreads();
    if (ticket_s == GRID - 1) {
        __threadfence();
        __shared__ float wsum[8];
        float acc = 0.f;
        for (int n = tid; n < NN; n += 512) {
            float sv = __hip_atomic_load(&sums[n], __ATOMIC_RELAXED,
                                         __HIP_MEMORY_SCOPE_AGENT);
            acc += logf(sv) - tgt[n];
        }
        #pragma unroll
        for (int m = 1; m < 64; m <<= 1) acc += __shfl_xor(acc, m);
        if ((tid & 63) == 0) wsum[tid >> 6] = acc;
        __syncthreads();
        if (tid == 0) {
            float t = 0.f;
            #pragma unroll
            for (int i = 0; i < 8; ++i) t += wsum[i];
            out[0] = t / (float)NN;
        }
    }
}

// ---------------------------------------------------------------------------
extern "C" void kernel_launch(void* const* d_in, const int* in_sizes, int n_in,
                              void* d_out, int out_size, void* d_ws, size_t ws_size,
                              hipStream_t stream)
{
    const float* qemb   = (const float*)d_in[0];
    const float* kemb   = (const float*)d_in[1];
    const int*   loc    = (const int*)d_in[2];
    const int*   labels = (const int*)d_in[3];
    float* out = (float*)d_out;

    char* ws = (char*)d_ws;
    __hip_bfloat16* Kn = (__hip_bfloat16*)ws;
    size_t off = (size_t)NV * D * 2;                       // 25.6 MB
    __hip_bfloat16* Qn = (__hip_bfloat16*)(ws + off);
    off += (size_t)NN * D * 2;                             // +0.5 MB
    float* sums = (float*)(ws + off); off += (size_t)NN * 4;
    float* tgt  = (float*)(ws + off); off += (size_t)NN * 4;
    unsigned int* counter = (unsigned int*)(ws + off);

    prep_kernel<<<2048, 256, 0, stream>>>(qemb, kemb, loc, labels,
                                          Kn, Qn, tgt, sums, counter);
    lse_main<<<GRID, 512, 0, stream>>>(Kn, Qn, tgt, sums, counter, out);
}

// Round 10
// 249.406 us; speedup vs baseline: 1.0875x; 1.0875x over previous
//
#include <hip/hip_runtime.h>
#include <hip/hip_bf16.h>

typedef __attribute__((ext_vector_type(4))) float f32x4;

namespace {
constexpr int D    = 128;
constexpr int SEQ  = 512;
constexpr int NV   = 100000;
constexpr int NN   = 2048;
constexpr int KC   = 64;                     // keys per LDS chunk
constexpr int CHUNK_B = KC * D;              // 8192 B (fp8: 1 B/elem)
constexpr int NCHUNK  = 1563;                // ceil(NV/KC)
constexpr int CPS     = 13;                  // chunks per slice (contiguous)
constexpr int NSLICE  = 121;                 // 121*13 = 1573 >= 1563
constexpr int MBLKS   = 8;                   // M blocks of 256 rows
constexpr int GRID    = MBLKS * NSLICE;      // 968; 968/8 = 121 exact (XCD)
constexpr float LOG2E = 1.4426950408889634f;
constexpr float EPSN  = 1e-12f;
}

// ---------------------------------------------------------------------------
// Prep (fused): normalize keys -> fp8 e4m3 Kf8[V][128B], rows stored with an
// 8B-granule XOR permutation (byte o -> o ^ ((row&15)<<3)) so lse's LINEAR
// global_load_lds staging lands a bank-conflict-mitigated layout in LDS
// (rule #21: permutation applied at the producer, read applies same XOR).
// Queries: gather+normalize, scale by log2(e), fp8 -> Qf8[N][128B] linear;
// also tgt[n] = cos(q,k_label) in full fp32. Zeroes sums + ticket counter.
// 2 rows/wave, float4 loads, cvt_pk_fp8 packing (4 floats -> 4B per lane).
// ---------------------------------------------------------------------------
__global__ __launch_bounds__(256)
void prep_kernel(const float* __restrict__ qemb,
                 const float* __restrict__ kemb,
                 const int*   __restrict__ loc,
                 const int*   __restrict__ labels,
                 unsigned char* __restrict__ Kf8,
                 unsigned char* __restrict__ Qf8,
                 float* __restrict__ tgt,
                 float* __restrict__ sums,
                 unsigned int* __restrict__ counter)
{
    const int tid  = threadIdx.x;
    const int gid0 = blockIdx.x * 256 + tid;
    if (gid0 < NN) sums[gid0] = 0.f;
    if (gid0 == NN) *counter = 0u;

    const int lane = tid & 63;
    const int half = lane >> 5;          // which of the wave's 2 rows
    const int l32  = lane & 31;
    const int wv0  = gid0 >> 6;
    const int nwv  = (gridDim.x * 256) >> 6;

    for (int wv = wv0; wv * 2 < NV + NN; wv += nwv) {
        const int row = wv * 2 + half;   // NV+NN even -> always valid

        if (row < NV) {                  // ---- key row ----
            const float* src = kemb + (size_t)row * D;
            float4 v = *(const float4*)(src + l32 * 4);
            float ss = v.x * v.x + v.y * v.y + v.z * v.z + v.w * v.w;
            #pragma unroll
            for (int m = 1; m < 32; m <<= 1) ss += __shfl_xor(ss, m);
            float inv = 1.0f / fmaxf(sqrtf(ss), EPSN);
            int p = __builtin_amdgcn_cvt_pk_fp8_f32(v.x * inv, v.y * inv, 0, false);
            p     = __builtin_amdgcn_cvt_pk_fp8_f32(v.z * inv, v.w * inv, p, true);
            const int off = (l32 * 4) ^ ((row & 15) << 3);   // 8B-granule XOR
            *(unsigned int*)(Kf8 + (size_t)row * 128 + off) = (unsigned int)p;
        } else {                         // ---- query row (+ tgt) ----
            const int n = row - NV;
            const int b = loc[2 * n], s = loc[2 * n + 1];
            const float* q = qemb + ((size_t)b * SEQ + s) * D;
            const float* k = kemb + (size_t)labels[n] * D;
            float4 qv = *(const float4*)(q + l32 * 4);
            float4 kv = *(const float4*)(k + l32 * 4);
            float qq = qv.x * qv.x + qv.y * qv.y + qv.z * qv.z + qv.w * qv.w;
            float kk = kv.x * kv.x + kv.y * kv.y + kv.z * kv.z + kv.w * kv.w;
            float qk = qv.x * kv.x + qv.y * kv.y + qv.z * kv.z + qv.w * kv.w;
            #pragma unroll
            for (int m = 1; m < 32; m <<= 1) {
                qq += __shfl_xor(qq, m);
                kk += __shfl_xor(kk, m);
                qk += __shfl_xor(qk, m);
            }
            float invq = 1.0f / fmaxf(sqrtf(qq), EPSN);
            float scl  = LOG2E * invq;
            int p = __builtin_amdgcn_cvt_pk_fp8_f32(qv.x * scl, qv.y * scl, 0, false);
            p     = __builtin_amdgcn_cvt_pk_fp8_f32(qv.z * scl, qv.w * scl, p, true);
            *(unsigned int*)(Qf8 + (size_t)n * 128 + l32 * 4) = (unsigned int)p;
            if (l32 == 0)
                tgt[n] = qk * invq / fmaxf(sqrtf(kk), EPSN);
        }
    }
}

// ---------------------------------------------------------------------------
// Main: r5's proven schedule (67us, best observed) ported to fp8 e4m3.
// 512 threads = 8 waves x 32 rows. qf as long[2][4] = 16 VGPR (half of bf16)
// -> ample margin under __launch_bounds__(512,4)'s 128 budget (r5 measured
// VGPR=60 at the bf16 version of this exact shape; spill tripwire=WRITE).
// fp8 chunk = 8 KB -> ring-4 = 32 KB -> up to 4 blocks/CU (32 waves).
// Depth-3 prefetch, CORRECTLY counted vmcnt (r9 lesson: the awaited load
// must have been issued >= latency ago): 1 glds/wave/stage, outstanding
// {c+1,c+2,c+3} -> vmcnt(2) waits on a load issued 2 full KC=64 iterations
// (~1200cy) earlier = free. r5's vmcnt(4) was accidentally vacuous (racy);
// this one is both counted AND safe.
// LDS reads: ds_read_b64 at addr = kic*128 + ((ds2*32+lh*8) ^ (lr<<3))
// matching prep's row permutation -> max 4-way bank conflict (1.58x).
// MFMA: mfma_f32_16x16x32_fp8_fp8 (same rate/count as bf16; half operands).
// rowsum += exp2(logit): |logit|<=~1.6 -> fixed-shift LSE, no running max.
// Last-finished block (ticket) computes the final mean inline.
// ---------------------------------------------------------------------------
__global__ __launch_bounds__(512, 4)
void lse_main(const unsigned char* __restrict__ Kf8,
              const unsigned char* __restrict__ Qf8,
              const float* __restrict__ tgt,
              float* __restrict__ sums,
              unsigned int* __restrict__ counter,
              float* __restrict__ out)
{
    __shared__ char lds[4 * CHUNK_B];   // 32 KB ring
    const int tid  = threadIdx.x;
    const int lane = tid & 63;
    const int lr   = lane & 15;
    const int lh   = lane >> 4;
    const int w    = tid >> 6;          // wave 0..7

    // Bijective XCD decode (968 = 8*121 exact): XCD x owns lins
    // [121x, 121x+121) -> ~15 consecutive slices incl. all 8 M-blocks.
    const int bid = blockIdx.x;
    const int lin = (bid & 7) * 121 + (bid >> 3);
    const int slice = lin >> 3;          // 0..120
    const int mblk  = lin & 7;           // 0..7

    const int chunk0 = slice * CPS;
    const int nch = min(CPS, NCHUNK - chunk0);   // 13, slice 120 -> 3
    const int m0 = mblk * 256 + w * 32;

    // async stage of chunk c into ring buffer bi: LINEAR LDS dest and
    // LINEAR global source (prep already row-permuted Kf8).
    auto stage = [&](int c, int bi) {
        const int keybase = (chunk0 + c) * KC;
        const int kic_l = w * 8 + (lane >> 3);       // key row 0..63
        const int key = min(keybase + kic_l, NV - 1);
        const unsigned char* g = Kf8 + (size_t)key * 128 + (lane & 7) * 16;
        const char* l = lds + bi * CHUNK_B + w * 1024;   // wave-uniform base
        __builtin_amdgcn_global_load_lds(
            (const __attribute__((address_space(1))) void*)g,
            (__attribute__((address_space(3))) void*)l, 16, 0, 0);
    };

    stage(0, 0);
    if (nch > 1) stage(1, 1);
    if (nch > 2) stage(2, 2);            // prologue depth-3

    // A-operand (Q) fragments: row m0+rg*16+lr, k-bytes [ds*32+lh*8, +8)
    long qf[2][4];
    #pragma unroll
    for (int rg = 0; rg < 2; ++rg)
        #pragma unroll
        for (int ds = 0; ds < 4; ++ds)
            qf[rg][ds] = *(const long*)(Qf8 +
                          (size_t)(m0 + rg * 16 + lr) * 128 + ds * 32 + lh * 8);

    float rowsum[2][4] = {};
    __syncthreads();   // one-time full drain (prologue stages + qf loads)

    for (int c = 0; c < nch; ++c) {
        if (c + 3 < nch) stage(c + 3, (c + 3) & 3);   // depth-3 prefetch

        const char* buf = lds + (c & 3) * CHUNK_B;
        const int vbase = (chunk0 + c) * KC;
        const bool full = (vbase + KC <= NV);
        #pragma unroll
        for (int kg = 0; kg < 4; ++kg) {
            const int kic = kg * 16 + lr;        // key row within chunk
            f32x4 acc[2] = {{0,0,0,0},{0,0,0,0}};
            #pragma unroll
            for (int ds2 = 0; ds2 < 4; ++ds2) {
                long bf = *(const long*)(buf + kic * 128 +
                             (((ds2 * 32 + lh * 8)) ^ (lr << 3)));
                #pragma unroll
                for (int rg = 0; rg < 2; ++rg)
                    acc[rg] = __builtin_amdgcn_mfma_f32_16x16x32_fp8_fp8(
                                  qf[rg][ds2], bf, acc[rg], 0, 0, 0);
            }
            if (full) {
                #pragma unroll
                for (int rg = 0; rg < 2; ++rg)
                    #pragma unroll
                    for (int j = 0; j < 4; ++j)
                        rowsum[rg][j] += __builtin_amdgcn_exp2f(acc[rg][j]);
            } else {
                const bool ok = (vbase + kic) < NV;   // col = lr on output
                #pragma unroll
                for (int rg = 0; rg < 2; ++rg)
                    #pragma unroll
                    for (int j = 0; j < 4; ++j)
                        rowsum[rg][j] += ok ? __builtin_amdgcn_exp2f(acc[rg][j]) : 0.f;
            }
        }
        // counted wait: ensure stage(c+1) (issued 2 iterations ago) landed;
        // newer stages stay in flight across the barrier.
        if (c + 3 < nch) {
            asm volatile("s_waitcnt vmcnt(2)" ::: "memory");
            __builtin_amdgcn_s_barrier();
            asm volatile("" ::: "memory");
        } else if (c + 3 == nch) {
            asm volatile("s_waitcnt vmcnt(1)" ::: "memory");
            __builtin_amdgcn_s_barrier();
            asm volatile("" ::: "memory");
        } else if (c + 2 == nch) {
            asm volatile("s_waitcnt vmcnt(0)" ::: "memory");
            __builtin_amdgcn_s_barrier();
            asm volatile("" ::: "memory");
        }   // c == nch-1: no further LDS reuse, no wait needed
    }

    // reduce partial sums across the 16 column-lanes, one atomic per row
    #pragma unroll
    for (int rg = 0; rg < 2; ++rg)
        #pragma unroll
        for (int j = 0; j < 4; ++j) {
            float v = rowsum[rg][j];
            v += __shfl_xor(v, 1);
            v += __shfl_xor(v, 2);
            v += __shfl_xor(v, 4);
            v += __shfl_xor(v, 8);
            if (lr == 0)
                atomicAdd(&sums[m0 + rg * 16 + lh * 4 + j], v);
        }

    // ---- last-block final reduction (fused final_kernel) ----
    __threadfence();                       // my atomics visible before ticket
    __syncthreads();
    __shared__ int ticket_s;
    if (tid == 0) ticket_s = (int)atomicAdd(counter, 1u);
    __syncthreads();
    if (ticket_s == GRID - 1) {
        __threadfence();
        __shared__ float wsum[8];
        float acc = 0.f;
        for (int n = tid; n < NN; n += 512) {
            float sv = __hip_atomic_load(&sums[n], __ATOMIC_RELAXED,
                                         __HIP_MEMORY_SCOPE_AGENT);
            acc += logf(sv) - tgt[n];
        }
        #pragma unroll
        for (int m = 1; m < 64; m <<= 1) acc += __shfl_xor(acc, m);
        if ((tid & 63) == 0) wsum[tid >> 6] = acc;
        __syncthreads();
        if (tid == 0) {
            float t = 0.f;
            #pragma unroll
            for (int i = 0; i < 8; ++i) t += wsum[i];
            out[0] = t / (float)NN;
        }
    }
}

// ---------------------------------------------------------------------------
extern "C" void kernel_launch(void* const* d_in, const int* in_sizes, int n_in,
                              void* d_out, int out_size, void* d_ws, size_t ws_size,
                              hipStream_t stream)
{
    const float* qemb   = (const float*)d_in[0];
    const float* kemb   = (const float*)d_in[1];
    const int*   loc    = (const int*)d_in[2];
    const int*   labels = (const int*)d_in[3];
    float* out = (float*)d_out;

    char* ws = (char*)d_ws;
    unsigned char* Kf8 = (unsigned char*)ws;
    size_t off = (size_t)NV * 128;                         // 12.8 MB
    unsigned char* Qf8 = (unsigned char*)(ws + off);
    off += (size_t)NN * 128;                               // +0.26 MB
    float* sums = (float*)(ws + off); off += (size_t)NN * 4;
    float* tgt  = (float*)(ws + off); off += (size_t)NN * 4;
    unsigned int* counter = (unsigned int*)(ws + off);

    prep_kernel<<<2048, 256, 0, stream>>>(qemb, kemb, loc, labels,
                                          Kf8, Qf8, tgt, sums, counter);
    lse_main<<<GRID, 512, 0, stream>>>(Kf8, Qf8, tgt, sums, counter, out);
}